// Round 4
// baseline (469.540 us; speedup 1.0000x reference)
//
#include <hip/hip_runtime.h>

#define DD    768
#define OUTN  196
#define KHALF 384         // k elems per LDS stage (768 = 2 stages)
#define SSLOT 48          // 16B granules per row per stage (384 halfs / 8)

typedef __attribute__((ext_vector_type(8))) _Float16 halfx8;
typedef __attribute__((ext_vector_type(4))) float    f32x4;

// Prep: Wh[n][k] = fp16(W[n][k]*gamma[k]);  Ssum[n] = sum_k (float)Wh[n][k]
// (sum of ROUNDED values so the mean-subtraction fold is exact);
// cvec[n] = b[n] + sum_k beta[k]*W[n][k].
__global__ __launch_bounds__(256) void wprep_kernel(
    const float* __restrict__ W, const float* __restrict__ gamma,
    const float* __restrict__ beta, const float* __restrict__ bias,
    _Float16* __restrict__ Wh, float* __restrict__ Ssum, float* __restrict__ cvec)
{
    __shared__ float red[2][4];
    const int n   = blockIdx.x;
    const int tid = threadIdx.x;
    float s1 = 0.f, s2 = 0.f;
#pragma unroll
    for (int kk = 0; kk < 3; ++kk) {
        const int k = tid + kk * 256;
        const float w = W[n * DD + k];
        const _Float16 h = (_Float16)(w * gamma[k]);
        Wh[n * DD + k] = h;
        s1 += (float)h;
        s2 += beta[k] * w;
    }
#pragma unroll
    for (int off = 32; off > 0; off >>= 1) {
        s1 += __shfl_xor(s1, off);
        s2 += __shfl_xor(s2, off);
    }
    if ((tid & 63) == 0) { red[0][tid >> 6] = s1; red[1][tid >> 6] = s2; }
    __syncthreads();
    if (tid == 0) {
        Ssum[n] = red[0][0] + red[0][1] + red[0][2] + red[0][3];
        cvec[n] = bias[n] + red[1][0] + red[1][1] + red[1][2] + red[1][3];
    }
}

// One block = 1024 threads = 16 waves; W N-part staged in LDS in TWO k-halves
// of 384 so LDS = 61,440 B -> 2 blocks/CU -> 32 waves/CU (max occupancy).
// Each wave owns 16 rows; per-stage k-loop has no barriers, no global W loads.
// LDS layout per stage: row r (part-local, stride 384 halfs = 768 B), 16B-slot
// s stored at s^(r&7): conflict-minimal ds_read_b128 for the MFMA B-fragment.
template <int T, int N0, int PR>
__device__ __forceinline__ void run_part(
    const float* __restrict__ x, const _Float16* __restrict__ Wh,
    const float* __restrict__ Ssum, const float* __restrict__ cvec,
    float* __restrict__ out, _Float16* ldsW, int mblk)
{
    const int tid  = threadIdx.x;
    const int wv   = tid >> 6;
    const int lane = tid & 63;
    const int ln16 = lane & 15;
    const int q    = lane >> 4;
    const int rx   = ln16 & 7;                     // (tile*16+ln16)&7 == ln16&7

    const long row0 = (long)mblk * 256 + wv * 16;  // this wave's 16 rows
    const float* xp = x + (row0 + ln16) * DD + q * 8;

    int rbase[T];                                  // per-tile LDS row base (elems)
#pragma unroll
    for (int t = 0; t < T; ++t) rbase[t] = (t * 16 + ln16) * KHALF;

    f32x4 acc[T];
#pragma unroll
    for (int t = 0; t < T; ++t) acc[t] = (f32x4){0.f, 0.f, 0.f, 0.f};

    float s = 0.f, ss = 0.f;

    for (int ks = 0; ks < 2; ++ks) {
        // ---- stage this k-half of the W part into LDS
        for (int ci = tid; ci < SSLOT * PR; ci += 1024) {
            const int r  = ci / SSLOT;
            const int sl = ci - r * SSLOT;
            int nrow = N0 + r;
            if (nrow > OUTN - 1) nrow = OUTN - 1;  // clamp pad rows (never stored)
            const halfx8 w = *(const halfx8*)(Wh + nrow * DD + ks * KHALF + sl * 8);
            *(halfx8*)(ldsW + (r * SSLOT + (sl ^ (r & 7))) * 8) = w;
        }
        __syncthreads();

#pragma unroll
        for (int kt2 = 0; kt2 < 12; ++kt2) {
            const int kt = ks * 12 + kt2;
            const float4 v0 = *(const float4*)(xp + kt * 32);
            const float4 v1 = *(const float4*)(xp + kt * 32 + 4);
            s  += (v0.x + v0.y) + (v0.z + v0.w) + (v1.x + v1.y) + (v1.z + v1.w);
            ss  = fmaf(v0.x, v0.x, ss); ss = fmaf(v0.y, v0.y, ss);
            ss  = fmaf(v0.z, v0.z, ss); ss = fmaf(v0.w, v0.w, ss);
            ss  = fmaf(v1.x, v1.x, ss); ss = fmaf(v1.y, v1.y, ss);
            ss  = fmaf(v1.z, v1.z, ss); ss = fmaf(v1.w, v1.w, ss);

            halfx8 hi, lo;
            hi[0] = (_Float16)v0.x; lo[0] = (_Float16)(v0.x - (float)hi[0]);
            hi[1] = (_Float16)v0.y; lo[1] = (_Float16)(v0.y - (float)hi[1]);
            hi[2] = (_Float16)v0.z; lo[2] = (_Float16)(v0.z - (float)hi[2]);
            hi[3] = (_Float16)v0.w; lo[3] = (_Float16)(v0.w - (float)hi[3]);
            hi[4] = (_Float16)v1.x; lo[4] = (_Float16)(v1.x - (float)hi[4]);
            hi[5] = (_Float16)v1.y; lo[5] = (_Float16)(v1.y - (float)hi[5]);
            hi[6] = (_Float16)v1.z; lo[6] = (_Float16)(v1.z - (float)hi[6]);
            hi[7] = (_Float16)v1.w; lo[7] = (_Float16)(v1.w - (float)hi[7]);

#pragma unroll
            for (int t = 0; t < T; ++t) {
                const int slot = (kt2 * 4 + q) ^ rx;
                const halfx8 bw = *(const halfx8*)(ldsW + rbase[t] + slot * 8);
                acc[t] = __builtin_amdgcn_mfma_f32_16x16x32_f16(hi, bw, acc[t], 0, 0, 0);
                acc[t] = __builtin_amdgcn_mfma_f32_16x16x32_f16(lo, bw, acc[t], 0, 0, 0);
            }
        }
        __syncthreads();   // all waves done reading this stage before re-stage
    }

    // ---- row stats: lane's row lives in 4 lanes (q=0..3) -> 2 xors each
    s  += __shfl_xor(s, 16);  s  += __shfl_xor(s, 32);
    ss += __shfl_xor(ss, 16); ss += __shfl_xor(ss, 32);
    const float mean_r = s * (1.f / DD);
    const float rstd_r = rsqrtf(ss * (1.f / DD) - mean_r * mean_r + 1e-6f);

    float mb[4], rb[4];
#pragma unroll
    for (int rg = 0; rg < 4; ++rg) {              // stats for output rows q*4+rg
        mb[rg] = __shfl(mean_r, q * 4 + rg);
        rb[rg] = __shfl(rstd_r, q * 4 + rg);
    }

    const long obase = (row0 + q * 4) * OUTN;
#pragma unroll
    for (int t = 0; t < T; ++t) {
        const int n = N0 + t * 16 + ln16;
        if (n < OUTN) {
            const float Sp = Ssum[n];
            const float cn = cvec[n];
#pragma unroll
            for (int rg = 0; rg < 4; ++rg)
                out[obase + rg * OUTN + n] = rb[rg] * (acc[t][rg] - mb[rg] * Sp) + cn;
        }
    }
}

__global__ __launch_bounds__(1024, 8) void fused_ln_linear(
    const float* __restrict__ x, const _Float16* __restrict__ Wh,
    const float* __restrict__ Ssum, const float* __restrict__ cvec,
    float* __restrict__ out)
{
    __shared__ _Float16 ldsW[80 * KHALF];         // 61,440 B -> 2 blocks/CU
    const int part = blockIdx.x % 3;              // 3 consecutive bids share m -> L3 reuse
    const int m    = blockIdx.x / 3;
    if (part == 0)      run_part<5,   0, 80>(x, Wh, Ssum, cvec, out, ldsW, m);
    else if (part == 1) run_part<4,  80, 64>(x, Wh, Ssum, cvec, out, ldsW, m);
    else                run_part<4, 144, 64>(x, Wh, Ssum, cvec, out, ldsW, m);
}

extern "C" void kernel_launch(void* const* d_in, const int* in_sizes, int n_in,
                              void* d_out, int out_size, void* d_ws, size_t ws_size,
                              hipStream_t stream) {
    const float* x     = (const float*)d_in[0];
    const float* gamma = (const float*)d_in[1];
    const float* beta  = (const float*)d_in[2];
    const float* W     = (const float*)d_in[3];
    const float* b     = (const float*)d_in[4];
    float* out = (float*)d_out;

    _Float16* Wh = (_Float16*)d_ws;                                   // 301,056 B
    float*    Ss = (float*)((char*)d_ws + OUTN * DD * sizeof(_Float16));
    float*    cv = Ss + OUTN;

    wprep_kernel<<<OUTN, 256, 0, stream>>>(W, gamma, beta, b, Wh, Ss, cv);

    // 65536 rows / 256 rows-per-block = 256 m-chunks, x3 N-parts
    fused_ln_linear<<<256 * 3, 1024, 0, stream>>>(x, Wh, Ss, cv, out);
}

// Round 5
// 355.997 us; speedup vs baseline: 1.3189x; 1.3189x over previous
//
#include <hip/hip_runtime.h>

#define DD    768
#define OUTN  196
#define KHALF 384         // k elems per LDS stage (768 = 2 stages)
#define SSLOT 48          // 16B granules per row per stage (384 halfs / 8)

typedef __attribute__((ext_vector_type(8))) _Float16 halfx8;
typedef __attribute__((ext_vector_type(4))) float    f32x4;

// Prep: Wh[n][k] = fp16(W[n][k]*gamma[k]);  Ssum[n] = sum_k (float)Wh[n][k]
// (sum of ROUNDED values so the mean-subtraction fold is exact);
// cvec[n] = b[n] + sum_k beta[k]*W[n][k].
__global__ __launch_bounds__(256) void wprep_kernel(
    const float* __restrict__ W, const float* __restrict__ gamma,
    const float* __restrict__ beta, const float* __restrict__ bias,
    _Float16* __restrict__ Wh, float* __restrict__ Ssum, float* __restrict__ cvec)
{
    __shared__ float red[2][4];
    const int n   = blockIdx.x;
    const int tid = threadIdx.x;
    float s1 = 0.f, s2 = 0.f;
#pragma unroll
    for (int kk = 0; kk < 3; ++kk) {
        const int k = tid + kk * 256;
        const float w = W[n * DD + k];
        const _Float16 h = (_Float16)(w * gamma[k]);
        Wh[n * DD + k] = h;
        s1 += (float)h;
        s2 += beta[k] * w;
    }
#pragma unroll
    for (int off = 32; off > 0; off >>= 1) {
        s1 += __shfl_xor(s1, off);
        s2 += __shfl_xor(s2, off);
    }
    if ((tid & 63) == 0) { red[0][tid >> 6] = s1; red[1][tid >> 6] = s2; }
    __syncthreads();
    if (tid == 0) {
        Ssum[n] = red[0][0] + red[0][1] + red[0][2] + red[0][3];
        cvec[n] = bias[n] + red[1][0] + red[1][1] + red[1][2] + red[1][3];
    }
}

// One block = 1024 threads = 16 waves; W N-part staged in LDS in TWO k-halves
// of 384 so LDS = 61,440 B -> 2 blocks/CU by LDS. Launch bound stays (1024,4)
// so the register allocator is NOT squeezed (round-4 lesson: forcing 8 waves/EU
// produced 32-VGPR spilling code, +430 MB scratch traffic). Round-3 codegen was
// 52 VGPR at this bound -> <=64 -> 2 blocks/CU co-residency happens naturally.
// Each wave owns 16 rows; per-stage k-loop has no barriers, no global W loads.
// LDS layout per stage: row r (part-local, stride 384 halfs = 768 B), 16B-slot
// s stored at s^(r&7): conflict-minimal ds_read_b128 for the MFMA B-fragment.
template <int T, int N0, int PR>
__device__ __forceinline__ void run_part(
    const float* __restrict__ x, const _Float16* __restrict__ Wh,
    const float* __restrict__ Ssum, const float* __restrict__ cvec,
    float* __restrict__ out, _Float16* ldsW, int mblk)
{
    const int tid  = threadIdx.x;
    const int wv   = tid >> 6;
    const int lane = tid & 63;
    const int ln16 = lane & 15;
    const int q    = lane >> 4;
    const int rx   = ln16 & 7;                     // (tile*16+ln16)&7 == ln16&7

    const long row0 = (long)mblk * 256 + wv * 16;  // this wave's 16 rows
    const float* xp = x + (row0 + ln16) * DD + q * 8;

    int rbase[T];                                  // per-tile LDS row base (elems)
#pragma unroll
    for (int t = 0; t < T; ++t) rbase[t] = (t * 16 + ln16) * KHALF;

    f32x4 acc[T];
#pragma unroll
    for (int t = 0; t < T; ++t) acc[t] = (f32x4){0.f, 0.f, 0.f, 0.f};

    float s = 0.f, ss = 0.f;

    for (int ks = 0; ks < 2; ++ks) {
        // ---- stage this k-half of the W part into LDS
        for (int ci = tid; ci < SSLOT * PR; ci += 1024) {
            const int r  = ci / SSLOT;
            const int sl = ci - r * SSLOT;
            int nrow = N0 + r;
            if (nrow > OUTN - 1) nrow = OUTN - 1;  // clamp pad rows (never stored)
            const halfx8 w = *(const halfx8*)(Wh + nrow * DD + ks * KHALF + sl * 8);
            *(halfx8*)(ldsW + (r * SSLOT + (sl ^ (r & 7))) * 8) = w;
        }
        __syncthreads();

#pragma unroll
        for (int kt2 = 0; kt2 < 12; ++kt2) {
            const int kt = ks * 12 + kt2;
            const float4 v0 = *(const float4*)(xp + kt * 32);
            const float4 v1 = *(const float4*)(xp + kt * 32 + 4);
            s  += (v0.x + v0.y) + (v0.z + v0.w) + (v1.x + v1.y) + (v1.z + v1.w);
            ss  = fmaf(v0.x, v0.x, ss); ss = fmaf(v0.y, v0.y, ss);
            ss  = fmaf(v0.z, v0.z, ss); ss = fmaf(v0.w, v0.w, ss);
            ss  = fmaf(v1.x, v1.x, ss); ss = fmaf(v1.y, v1.y, ss);
            ss  = fmaf(v1.z, v1.z, ss); ss = fmaf(v1.w, v1.w, ss);

            halfx8 hi, lo;
            hi[0] = (_Float16)v0.x; lo[0] = (_Float16)(v0.x - (float)hi[0]);
            hi[1] = (_Float16)v0.y; lo[1] = (_Float16)(v0.y - (float)hi[1]);
            hi[2] = (_Float16)v0.z; lo[2] = (_Float16)(v0.z - (float)hi[2]);
            hi[3] = (_Float16)v0.w; lo[3] = (_Float16)(v0.w - (float)hi[3]);
            hi[4] = (_Float16)v1.x; lo[4] = (_Float16)(v1.x - (float)hi[4]);
            hi[5] = (_Float16)v1.y; lo[5] = (_Float16)(v1.y - (float)hi[5]);
            hi[6] = (_Float16)v1.z; lo[6] = (_Float16)(v1.z - (float)hi[6]);
            hi[7] = (_Float16)v1.w; lo[7] = (_Float16)(v1.w - (float)hi[7]);

#pragma unroll
            for (int t = 0; t < T; ++t) {
                const int slot = (kt2 * 4 + q) ^ rx;
                const halfx8 bw = *(const halfx8*)(ldsW + rbase[t] + slot * 8);
                acc[t] = __builtin_amdgcn_mfma_f32_16x16x32_f16(hi, bw, acc[t], 0, 0, 0);
                acc[t] = __builtin_amdgcn_mfma_f32_16x16x32_f16(lo, bw, acc[t], 0, 0, 0);
            }
        }
        __syncthreads();   // all waves done reading this stage before re-stage
    }

    // ---- row stats: lane's row lives in 4 lanes (q=0..3) -> 2 xors each
    s  += __shfl_xor(s, 16);  s  += __shfl_xor(s, 32);
    ss += __shfl_xor(ss, 16); ss += __shfl_xor(ss, 32);
    const float mean_r = s * (1.f / DD);
    const float rstd_r = rsqrtf(ss * (1.f / DD) - mean_r * mean_r + 1e-6f);

    float mb[4], rb[4];
#pragma unroll
    for (int rg = 0; rg < 4; ++rg) {              // stats for output rows q*4+rg
        mb[rg] = __shfl(mean_r, q * 4 + rg);
        rb[rg] = __shfl(rstd_r, q * 4 + rg);
    }

    const long obase = (row0 + q * 4) * OUTN;
#pragma unroll
    for (int t = 0; t < T; ++t) {
        const int n = N0 + t * 16 + ln16;
        if (n < OUTN) {
            const float Sp = Ssum[n];
            const float cn = cvec[n];
#pragma unroll
            for (int rg = 0; rg < 4; ++rg)
                out[obase + rg * OUTN + n] = rb[rg] * (acc[t][rg] - mb[rg] * Sp) + cn;
        }
    }
}

__global__ __launch_bounds__(1024, 4) void fused_ln_linear(
    const float* __restrict__ x, const _Float16* __restrict__ Wh,
    const float* __restrict__ Ssum, const float* __restrict__ cvec,
    float* __restrict__ out)
{
    __shared__ _Float16 ldsW[80 * KHALF];         // 61,440 B -> 2 blocks/CU by LDS
    const int part = blockIdx.x % 3;              // 3 consecutive bids share m -> L3 reuse
    const int m    = blockIdx.x / 3;
    if (part == 0)      run_part<5,   0, 80>(x, Wh, Ssum, cvec, out, ldsW, m);
    else if (part == 1) run_part<4,  80, 64>(x, Wh, Ssum, cvec, out, ldsW, m);
    else                run_part<4, 144, 64>(x, Wh, Ssum, cvec, out, ldsW, m);
}

extern "C" void kernel_launch(void* const* d_in, const int* in_sizes, int n_in,
                              void* d_out, int out_size, void* d_ws, size_t ws_size,
                              hipStream_t stream) {
    const float* x     = (const float*)d_in[0];
    const float* gamma = (const float*)d_in[1];
    const float* beta  = (const float*)d_in[2];
    const float* W     = (const float*)d_in[3];
    const float* b     = (const float*)d_in[4];
    float* out = (float*)d_out;

    _Float16* Wh = (_Float16*)d_ws;                                   // 301,056 B
    float*    Ss = (float*)((char*)d_ws + OUTN * DD * sizeof(_Float16));
    float*    cv = Ss + OUTN;

    wprep_kernel<<<OUTN, 256, 0, stream>>>(W, gamma, beta, b, Wh, Ss, cv);

    // 65536 rows / 256 rows-per-block = 256 m-chunks, x3 N-parts
    fused_ln_linear<<<256 * 3, 1024, 0, stream>>>(x, Wh, Ss, cv, out);
}